// Round 6
// baseline (384.591 us; speedup 1.0000x reference)
//
#include <hip/hip_runtime.h>
#include <hip/hip_bf16.h>

#define D 64
#define N_GRAPHS 128
#define D_OUT 16
#define BCAP 16384   // max edges per 256-node bucket (avg 6400)
#define TILE 4096    // edges per bin_kernel block

typedef unsigned short u16;
typedef unsigned int u32;
typedef unsigned char u8;

__device__ inline u16 f2bf(float f) {  // round-to-nearest-even
  u32 u = __float_as_uint(f);
  return (u16)((u + 0x7fffu + ((u >> 16) & 1u)) >> 16);
}
__device__ inline float bf2f(u16 b) { return __uint_as_float((u32)b << 16); }

// ===========================================================================
// x (fp32) -> bf16, 4 elems/thread. Block 0 also initializes CSR cursors
// (consumed by bin_kernel, which launches after us on the same stream).
// ===========================================================================
__global__ __launch_bounds__(256) void cvt_bf16_kernel(
    const float* __restrict__ in, u16* __restrict__ out, int n4,
    int* __restrict__ cursors, int nbuck) {
  if (blockIdx.x == 0 && threadIdx.x < (u32)nbuck) cursors[threadIdx.x] = threadIdx.x * BCAP;
  int i = blockIdx.x * 256 + threadIdx.x;
  if (i >= n4) return;
  float4 v = ((const float4*)in)[i];
  ushort4 o;
  o.x = f2bf(v.x); o.y = f2bf(v.y); o.z = f2bf(v.z); o.w = f2bf(v.w);
  ((ushort4*)out)[i] = o;
}

// ===========================================================================
// CSR build: LDS counting sort (R5 structure — killed fill_kernel's 81MB
// partial-line writeback). Pass 1 bins edges by dst>>8 into global buckets
// with contiguous writes; pass 2 builds each bucket's CSR segment in LDS.
// ===========================================================================
__global__ __launch_bounds__(256) void bin_kernel(
    const int* __restrict__ src, const int* __restrict__ dst,
    int* __restrict__ cursors, u32* __restrict__ binned,
    int n_edges, int nbuck) {
  __shared__ u32 ent[TILE];
  __shared__ u8 ebk[TILE];
  __shared__ int hist[256];
  __shared__ int startb[256];
  __shared__ int cur[256];
  __shared__ int gbase[256];
  int t = threadIdx.x;
  hist[t] = 0;
  __syncthreads();

  int base = blockIdx.x * TILE;
  int cnt = n_edges - base;
  if (cnt > TILE) cnt = TILE;

  int mys[16], myd[16];
#pragma unroll
  for (int j = 0; j < 16; j++) {
    int i = base + t + j * 256;
    if (t + j * 256 < cnt) {
      mys[j] = src[i];
      myd[j] = dst[i];
      atomicAdd(&hist[myd[j] >> 8], 1);
    } else {
      myd[j] = -1;
    }
  }
  __syncthreads();
  int myc = hist[t];
  for (int off = 1; off < 256; off <<= 1) {
    int tmp = (t >= off) ? hist[t - off] : 0;
    __syncthreads();
    hist[t] += tmp;
    __syncthreads();
  }
  int excl = hist[t] - myc;
  startb[t] = excl;
  cur[t] = excl;
  __syncthreads();

#pragma unroll
  for (int j = 0; j < 16; j++) {
    if (myd[j] >= 0) {
      int b = myd[j] >> 8;
      int p = atomicAdd(&cur[b], 1);
      ent[p] = ((u32)myd[j] << 16) | (u32)mys[j];
      ebk[p] = (u8)b;
    }
  }
  __syncthreads();

  if (t < nbuck && myc > 0) gbase[t] = atomicAdd(&cursors[t], myc);
  __syncthreads();

#pragma unroll
  for (int j = 0; j < 16; j++) {
    int p = t + j * 256;
    if (p < cnt) {
      int b = ebk[p];
      int gpos = gbase[b] + (p - startb[b]);
      if (gpos < (b + 1) * BCAP) binned[gpos] = ent[p];
    }
  }
}

// Pass 2: one block per bucket. Recomputes the bucket-count prefix in LDS
// (196 values — cheaper than a separate scan kernel + launch gap), then
// builds the CSR segment in LDS and writes csr_src/offsets coalesced.
__global__ __launch_bounds__(256) void csr_kernel(
    const u32* __restrict__ binned, const int* __restrict__ cursors,
    u16* __restrict__ csr_src, int* __restrict__ offsets,
    int n_nodes, int nbuck) {
  __shared__ int deg[256];
  __shared__ int cur[256];
  __shared__ int pre[256];
  __shared__ u16 lcsr[BCAP];
  int b = blockIdx.x, t = threadIdx.x;

  // per-block scan of all bucket counts -> this bucket's edge base
  int c = 0;
  if (t < nbuck) {
    c = cursors[t] - t * BCAP;
    if (c < 0) c = 0;
    if (c > BCAP) c = BCAP;
  }
  pre[t] = c;
  __syncthreads();
  for (int off = 1; off < 256; off <<= 1) {
    int tmp = (t >= off) ? pre[t - off] : 0;
    __syncthreads();
    pre[t] += tmp;
    __syncthreads();
  }
  int cnt = cursors[b] - b * BCAP;
  if (cnt < 0) cnt = 0;
  if (cnt > BCAP) cnt = BCAP;
  int ebase = pre[b] - cnt;
  int nodeBase = b << 8;
  int nn = n_nodes - nodeBase;
  if (nn > 256) nn = 256;

  deg[t] = 0;
  __syncthreads();
  const u32* be = binned + (size_t)b * BCAP;
  for (int i = t; i < cnt; i += 256)
    atomicAdd(&deg[(be[i] >> 16) - nodeBase], 1);
  __syncthreads();
  int myd = deg[t];
  for (int off = 1; off < 256; off <<= 1) {
    int tmp = (t >= off) ? deg[t - off] : 0;
    __syncthreads();
    deg[t] += tmp;
    __syncthreads();
  }
  int loff = deg[t] - myd;
  cur[t] = loff;
  if (t < nn) offsets[nodeBase + t] = ebase + loff;
  if (b == nbuck - 1 && t == 0) offsets[n_nodes] = ebase + cnt;
  __syncthreads();

  for (int i = t; i < cnt; i += 256) {
    u32 e = be[i];
    int ln = (e >> 16) - nodeBase;
    int p = atomicAdd(&cur[ln], 1);
    lcsr[p] = (u16)(e & 0xffffu);
  }
  __syncthreads();
  for (int i = t; i < cnt; i += 256) csr_src[ebase + i] = lcsr[i];
}

// ===========================================================================
// Gather v5: TWO FEATURE PHASES for per-XCD L2 residency. Pass p covers
// feats [32p, 32p+32): working set = 50000*32*2B = 3.2MB < 4MB L2/XCD, so
// random row reads hit L2 (34.5 TB/s) instead of LLC. Grid = 2 x nb; blocks
// [0,nb) run pass 0, [nb,2nb) pass 1 (dispatch order separates the phases).
// Wave = node: 16 subgroups of 4 lanes, each lane 16B=8 bf16; x4 unroll.
// ===========================================================================
#define ACC8(a, r)                                                       \
  a[0] += __uint_as_float(r.x << 16); a[1] += __uint_as_float(r.x & 0xffff0000u); \
  a[2] += __uint_as_float(r.y << 16); a[3] += __uint_as_float(r.y & 0xffff0000u); \
  a[4] += __uint_as_float(r.z << 16); a[5] += __uint_as_float(r.z & 0xffff0000u); \
  a[6] += __uint_as_float(r.w << 16); a[7] += __uint_as_float(r.w & 0xffff0000u);

__global__ __launch_bounds__(256) void gather_kernel(
    const u16* __restrict__ h, const int* __restrict__ offsets,
    const u16* __restrict__ csr_src, float* __restrict__ agg,
    int n_nodes, int nb) {
  int pass = (blockIdx.x >= nb) ? 1 : 0;
  int blk = blockIdx.x - pass * nb;
  int node = blk * 4 + (threadIdx.x >> 6);
  int lane = threadIdx.x & 63;
  int sub = lane >> 2;                      // 0..15
  int fo = pass * 32 + (lane & 3) * 8;      // feature offset (8 bf16 = 16B)
  if (node >= n_nodes) return;
  int start = offsets[node];
  int end = offsets[node + 1];
  int len = end - start;
  int chunk = (len + 15) >> 4;
  int i = start + sub * chunk;
  int re = i + chunk;
  if (re > end) re = end;

  float a0[8] = {0,0,0,0,0,0,0,0}, a1[8] = {0,0,0,0,0,0,0,0};
  float a2[8] = {0,0,0,0,0,0,0,0}, a3[8] = {0,0,0,0,0,0,0,0};
  for (; i + 3 < re; i += 4) {
    int s0 = csr_src[i], s1 = csr_src[i + 1], s2 = csr_src[i + 2], s3 = csr_src[i + 3];
    uint4 r0 = *(const uint4*)(h + ((size_t)s0 << 6) + fo);
    uint4 r1 = *(const uint4*)(h + ((size_t)s1 << 6) + fo);
    uint4 r2 = *(const uint4*)(h + ((size_t)s2 << 6) + fo);
    uint4 r3 = *(const uint4*)(h + ((size_t)s3 << 6) + fo);
    ACC8(a0, r0) ACC8(a1, r1) ACC8(a2, r2) ACC8(a3, r3)
  }
  for (; i < re; i++) {
    int s0 = csr_src[i];
    uint4 r0 = *(const uint4*)(h + ((size_t)s0 << 6) + fo);
    ACC8(a0, r0)
  }
#pragma unroll
  for (int k = 0; k < 8; k++) a0[k] += a1[k] + a2[k] + a3[k];
#pragma unroll
  for (int k = 0; k < 8; k++) {
    a0[k] += __shfl_xor(a0[k], 4);
    a0[k] += __shfl_xor(a0[k], 8);
    a0[k] += __shfl_xor(a0[k], 16);
    a0[k] += __shfl_xor(a0[k], 32);
  }
  if (sub == 0) {
    float* ap = agg + ((size_t)node << 6) + fo;
    *(float4*)(ap)     = make_float4(a0[0], a0[1], a0[2], a0[3]);
    *(float4*)(ap + 4) = make_float4(a0[4], a0[5], a0[6], a0[7]);
  }
}

// ===========================================================================
// Dense: out = [relu](agg @ W_rel + b + h @ W_root). Weights in registers
// (lane o holds column o), readlane broadcast, zero LDS. agg fp32, h/out bf16.
// ===========================================================================
__global__ __launch_bounds__(64) void dense_kernel(
    const float* __restrict__ agg, const u16* __restrict__ h,
    const float* __restrict__ Wrel, const float* __restrict__ brel,
    const float* __restrict__ Wroot, u16* __restrict__ out,
    int n_nodes, int do_relu) {
  int lane = threadIdx.x;
  float wrel[D], wroot[D];
#pragma unroll
  for (int k = 0; k < D; k++) {
    wrel[k] = Wrel[k * D + lane];
    wroot[k] = Wroot[k * D + lane];
  }
  float b = brel[lane];

  for (int n = blockIdx.x; n < n_nodes; n += gridDim.x) {
    float va = agg[((size_t)n << 6) + lane];
    float vx = bf2f(h[((size_t)n << 6) + lane]);
    float acc = b;
#pragma unroll
    for (int k = 0; k < D; k++) {
      float sa = __int_as_float(__builtin_amdgcn_readlane(__float_as_int(va), k));
      float sx = __int_as_float(__builtin_amdgcn_readlane(__float_as_int(vx), k));
      acc = fmaf(sa, wrel[k], acc);
      acc = fmaf(sx, wroot[k], acc);
    }
    if (do_relu) acc = fmaxf(acc, 0.0f);
    out[((size_t)n << 6) + lane] = f2bf(acc);
  }
}

// ===========================================================================
// Pool + final fused: one block per graph. batch sorted -> binary-search the
// segment, reduce mean into LDS, then threads 0..15 apply the 64x16 linear.
// ===========================================================================
__global__ __launch_bounds__(256) void pool_final_kernel(
    const u16* __restrict__ h, const int* __restrict__ batch,
    const float* __restrict__ Wlin, const float* __restrict__ blin,
    float* __restrict__ out, int n_nodes) {
  __shared__ int seg[2];
  __shared__ float red[256];
  __shared__ float pm[D];
  int g = blockIdx.x;
  if (threadIdx.x < 2) {
    int target = g + (int)threadIdx.x;
    int lo = 0, hi = n_nodes;
    while (lo < hi) {
      int mid = (lo + hi) >> 1;
      if (batch[mid] < target) lo = mid + 1; else hi = mid;
    }
    seg[threadIdx.x] = lo;
  }
  __syncthreads();
  int start = seg[0], end = seg[1];
  int f = threadIdx.x & 63, sub = threadIdx.x >> 6;
  float acc = 0.0f;
  for (int n = start + sub; n < end; n += 4) acc += bf2f(h[((size_t)n << 6) + f]);
  red[threadIdx.x] = acc;
  __syncthreads();
  if (sub == 0) {
    float v = red[f] + red[64 + f] + red[128 + f] + red[192 + f];
    float cnt = (float)(end - start);
    pm[f] = v / fmaxf(cnt, 1.0f);
  }
  __syncthreads();
  if (threadIdx.x < D_OUT) {
    int o = threadIdx.x;
    float a = blin[o];
#pragma unroll
    for (int k = 0; k < D; k++) a = fmaf(pm[k], Wlin[k * D_OUT + o], a);
    out[g * D_OUT + o] = a;
  }
}

extern "C" void kernel_launch(void* const* d_in, const int* in_sizes, int n_in,
                              void* d_out, int out_size, void* d_ws, size_t ws_size,
                              hipStream_t stream) {
  const float* x     = (const float*)d_in[0];
  const int*   ei    = (const int*)d_in[1];
  const int*   batch = (const int*)d_in[3];
  const float* Wrel1 = (const float*)d_in[4];
  const float* brel1 = (const float*)d_in[5];
  const float* Wroot1= (const float*)d_in[6];
  const float* Wrel2 = (const float*)d_in[7];
  const float* brel2 = (const float*)d_in[8];
  const float* Wroot2= (const float*)d_in[9];
  const float* Wrel3 = (const float*)d_in[10];
  const float* brel3 = (const float*)d_in[11];
  const float* Wroot3= (const float*)d_in[12];
  const float* Wlin  = (const float*)d_in[13];
  const float* blin  = (const float*)d_in[14];
  float* out = (float*)d_out;

  const int n_edges = in_sizes[1] / 2;
  const int n_nodes = in_sizes[0] / D;
  const int* src = ei;
  const int* dst = ei + n_edges;
  const int nbuck = (n_nodes + 255) >> 8;  // 196

  // ---- workspace carve-up (binned and agg alias: binned dead after csr) ----
  char* p = (char*)d_ws;
  size_t binned_bytes = (size_t)nbuck * BCAP * sizeof(u32);
  size_t agg_bytes = (size_t)n_nodes * D * sizeof(float);
  u32* binned  = (u32*)p;
  float* agg   = (float*)p;
  p += (binned_bytes > agg_bytes ? binned_bytes : agg_bytes);
  int* cursors  = (int*)p;   p += 256 * sizeof(int);
  int* offsets  = (int*)p;   p += (size_t)(n_nodes + 4) * sizeof(int);
  u16* hX       = (u16*)p;   p += (size_t)n_nodes * D * sizeof(u16);
  u16* h1       = (u16*)p;   p += (size_t)n_nodes * D * sizeof(u16);
  u16* h2       = (u16*)p;   p += (size_t)n_nodes * D * sizeof(u16);
  u16* h3       = (u16*)p;   p += (size_t)n_nodes * D * sizeof(u16);
  u16* csr_src  = (u16*)p;   p += (size_t)n_edges * sizeof(u16);

  const int bin_blocks = (n_edges + TILE - 1) / TILE;
  const int nb = (n_nodes + 3) / 4;        // gather blocks per pass
  const int dense_blocks = 3072;
  const int cvt_n4 = n_nodes * D / 4;

  // ---- CSR build (LDS counting sort) + x->bf16 ----
  cvt_bf16_kernel<<<(cvt_n4 + 255) / 256, 256, 0, stream>>>(x, hX, cvt_n4, cursors, nbuck);
  bin_kernel<<<bin_blocks, 256, 0, stream>>>(src, dst, cursors, binned, n_edges, nbuck);
  csr_kernel<<<nbuck, 256, 0, stream>>>(binned, cursors, csr_src, offsets, n_nodes, nbuck);

  // ---- layer 1 ----
  gather_kernel<<<2 * nb, 256, 0, stream>>>(hX, offsets, csr_src, agg, n_nodes, nb);
  dense_kernel<<<dense_blocks, 64, 0, stream>>>(agg, hX, Wrel1, brel1, Wroot1, h1, n_nodes, 1);

  // ---- layer 2 ----
  gather_kernel<<<2 * nb, 256, 0, stream>>>(h1, offsets, csr_src, agg, n_nodes, nb);
  dense_kernel<<<dense_blocks, 64, 0, stream>>>(agg, h1, Wrel2, brel2, Wroot2, h2, n_nodes, 1);

  // ---- layer 3 (no relu) ----
  gather_kernel<<<2 * nb, 256, 0, stream>>>(h2, offsets, csr_src, agg, n_nodes, nb);
  dense_kernel<<<dense_blocks, 64, 0, stream>>>(agg, h2, Wrel3, brel3, Wroot3, h3, n_nodes, 0);

  // ---- pool + final linear (fused) ----
  pool_final_kernel<<<N_GRAPHS, 256, 0, stream>>>(h3, batch, Wlin, blin, out, n_nodes);
}

// Round 7
// 366.172 us; speedup vs baseline: 1.0503x; 1.0503x over previous
//
#include <hip/hip_runtime.h>
#include <hip/hip_bf16.h>

#define D 64
#define N_GRAPHS 128
#define D_OUT 16
#define BCAP 16384   // max edges per 256-node bucket (avg 6400)
#define TILE 4096    // edges per bin_kernel block

typedef unsigned short u16;
typedef unsigned int u32;
typedef unsigned char u8;

__device__ inline u16 f2bf(float f) {  // round-to-nearest-even
  u32 u = __float_as_uint(f);
  return (u16)((u + 0x7fffu + ((u >> 16) & 1u)) >> 16);
}
__device__ inline float bf2f(u16 b) { return __uint_as_float((u32)b << 16); }

// ===========================================================================
// x (fp32) -> bf16 into SPLIT half-tables: hLo[n][0:32], hHi[n][32:64].
// Separate arrays so a feature-phase touches only its own 128B cache lines
// (R6's interleaved layout thrashed L2: FETCH_SIZE 106MB for a 6.4MB table).
// Block 0 also initializes CSR cursors.
// ===========================================================================
__global__ __launch_bounds__(256) void cvt_bf16_kernel(
    const float* __restrict__ in, u16* __restrict__ lo, u16* __restrict__ hi,
    int n4, int* __restrict__ cursors, int nbuck) {
  if (blockIdx.x == 0 && threadIdx.x < (u32)nbuck) cursors[threadIdx.x] = threadIdx.x * BCAP;
  int i = blockIdx.x * 256 + threadIdx.x;
  if (i >= n4) return;
  float4 v = ((const float4*)in)[i];
  ushort4 o;
  o.x = f2bf(v.x); o.y = f2bf(v.y); o.z = f2bf(v.z); o.w = f2bf(v.w);
  int n = i >> 4, f4 = i & 15;  // 16 float4s per 64-feat row
  u16* d = (f4 < 8) ? (lo + n * 32 + f4 * 4) : (hi + n * 32 + (f4 - 8) * 4);
  *(ushort4*)d = o;
}

// ===========================================================================
// CSR build: LDS counting sort (R5 structure — killed fill_kernel's 81MB
// partial-line writeback). Pass 1 bins edges by dst>>8 with contiguous
// global writes; pass 2 builds each bucket's CSR segment in LDS.
// ===========================================================================
__global__ __launch_bounds__(256) void bin_kernel(
    const int* __restrict__ src, const int* __restrict__ dst,
    int* __restrict__ cursors, u32* __restrict__ binned,
    int n_edges, int nbuck) {
  __shared__ u32 ent[TILE];
  __shared__ u8 ebk[TILE];
  __shared__ int hist[256];
  __shared__ int startb[256];
  __shared__ int cur[256];
  __shared__ int gbase[256];
  int t = threadIdx.x;
  hist[t] = 0;
  __syncthreads();

  int base = blockIdx.x * TILE;
  int cnt = n_edges - base;
  if (cnt > TILE) cnt = TILE;

  int mys[16], myd[16];
#pragma unroll
  for (int j = 0; j < 16; j++) {
    int i = base + t + j * 256;
    if (t + j * 256 < cnt) {
      mys[j] = src[i];
      myd[j] = dst[i];
      atomicAdd(&hist[myd[j] >> 8], 1);
    } else {
      myd[j] = -1;
    }
  }
  __syncthreads();
  int myc = hist[t];
  for (int off = 1; off < 256; off <<= 1) {
    int tmp = (t >= off) ? hist[t - off] : 0;
    __syncthreads();
    hist[t] += tmp;
    __syncthreads();
  }
  int excl = hist[t] - myc;
  startb[t] = excl;
  cur[t] = excl;
  __syncthreads();

#pragma unroll
  for (int j = 0; j < 16; j++) {
    if (myd[j] >= 0) {
      int b = myd[j] >> 8;
      int p = atomicAdd(&cur[b], 1);
      ent[p] = ((u32)myd[j] << 16) | (u32)mys[j];
      ebk[p] = (u8)b;
    }
  }
  __syncthreads();

  if (t < nbuck && myc > 0) gbase[t] = atomicAdd(&cursors[t], myc);
  __syncthreads();

#pragma unroll
  for (int j = 0; j < 16; j++) {
    int p = t + j * 256;
    if (p < cnt) {
      int b = ebk[p];
      int gpos = gbase[b] + (p - startb[b]);
      if (gpos < (b + 1) * BCAP) binned[gpos] = ent[p];
    }
  }
}

// Pass 2: one block per bucket; recompute bucket-count prefix in LDS, build
// the bucket's CSR segment in LDS, write csr_src/offsets coalesced.
__global__ __launch_bounds__(256) void csr_kernel(
    const u32* __restrict__ binned, const int* __restrict__ cursors,
    u16* __restrict__ csr_src, int* __restrict__ offsets,
    int n_nodes, int nbuck) {
  __shared__ int deg[256];
  __shared__ int cur[256];
  __shared__ int pre[256];
  __shared__ u16 lcsr[BCAP];
  int b = blockIdx.x, t = threadIdx.x;

  int c = 0;
  if (t < nbuck) {
    c = cursors[t] - t * BCAP;
    if (c < 0) c = 0;
    if (c > BCAP) c = BCAP;
  }
  pre[t] = c;
  __syncthreads();
  for (int off = 1; off < 256; off <<= 1) {
    int tmp = (t >= off) ? pre[t - off] : 0;
    __syncthreads();
    pre[t] += tmp;
    __syncthreads();
  }
  int cnt = cursors[b] - b * BCAP;
  if (cnt < 0) cnt = 0;
  if (cnt > BCAP) cnt = BCAP;
  int ebase = pre[b] - cnt;
  int nodeBase = b << 8;
  int nn = n_nodes - nodeBase;
  if (nn > 256) nn = 256;

  deg[t] = 0;
  __syncthreads();
  const u32* be = binned + (size_t)b * BCAP;
  for (int i = t; i < cnt; i += 256)
    atomicAdd(&deg[(be[i] >> 16) - nodeBase], 1);
  __syncthreads();
  int myd = deg[t];
  for (int off = 1; off < 256; off <<= 1) {
    int tmp = (t >= off) ? deg[t - off] : 0;
    __syncthreads();
    deg[t] += tmp;
    __syncthreads();
  }
  int loff = deg[t] - myd;
  cur[t] = loff;
  if (t < nn) offsets[nodeBase + t] = ebase + loff;
  if (b == nbuck - 1 && t == 0) offsets[n_nodes] = ebase + cnt;
  __syncthreads();

  for (int i = t; i < cnt; i += 256) {
    u32 e = be[i];
    int ln = (e >> 16) - nodeBase;
    int p = atomicAdd(&cur[ln], 1);
    lcsr[p] = (u16)(e & 0xffffu);
  }
  __syncthreads();
  for (int i = t; i < cnt; i += 256) csr_src[ebase + i] = lcsr[i];
}

// ===========================================================================
// Gather v6: two feature phases over SPLIT half-tables. Pass p reads only
// table_p (3.2MB => fits 4MB per-XCD L2 in full 128B lines). Wave = node:
// 16 subgroups of 4 lanes; each lane 16B (8 bf16) => 4 lanes cover a 64B
// half-row. Chunked edge assignment + x2 unroll (avg deg/16sub = 2 edges).
// ===========================================================================
#define ACC8(a, r)                                                       \
  a[0] += __uint_as_float(r.x << 16); a[1] += __uint_as_float(r.x & 0xffff0000u); \
  a[2] += __uint_as_float(r.y << 16); a[3] += __uint_as_float(r.y & 0xffff0000u); \
  a[4] += __uint_as_float(r.z << 16); a[5] += __uint_as_float(r.z & 0xffff0000u); \
  a[6] += __uint_as_float(r.w << 16); a[7] += __uint_as_float(r.w & 0xffff0000u);

__global__ __launch_bounds__(256) void gather_kernel(
    const u16* __restrict__ hLo, const u16* __restrict__ hHi,
    const int* __restrict__ offsets, const u16* __restrict__ csr_src,
    float* __restrict__ agg, int n_nodes, int nb) {
  int pass = (blockIdx.x >= nb) ? 1 : 0;
  const u16* tab = pass ? hHi : hLo;
  int blk = blockIdx.x - pass * nb;
  int node = blk * 4 + (threadIdx.x >> 6);
  int lane = threadIdx.x & 63;
  int sub = lane >> 2;       // 0..15
  int fo = (lane & 3) * 8;   // within-half offset (8 bf16 = 16B)
  if (node >= n_nodes) return;
  int start = offsets[node];
  int end = offsets[node + 1];
  int len = end - start;
  int chunk = (len + 15) >> 4;
  int i = start + sub * chunk;
  int re = i + chunk;
  if (re > end) re = end;

  float a0[8] = {0,0,0,0,0,0,0,0}, a1[8] = {0,0,0,0,0,0,0,0};
  for (; i + 1 < re; i += 2) {
    int s0 = csr_src[i], s1 = csr_src[i + 1];
    uint4 r0 = *(const uint4*)(tab + ((size_t)s0 << 5) + fo);
    uint4 r1 = *(const uint4*)(tab + ((size_t)s1 << 5) + fo);
    ACC8(a0, r0) ACC8(a1, r1)
  }
  if (i < re) {
    int s0 = csr_src[i];
    uint4 r0 = *(const uint4*)(tab + ((size_t)s0 << 5) + fo);
    ACC8(a0, r0)
  }
#pragma unroll
  for (int k = 0; k < 8; k++) a0[k] += a1[k];
#pragma unroll
  for (int k = 0; k < 8; k++) {
    a0[k] += __shfl_xor(a0[k], 4);
    a0[k] += __shfl_xor(a0[k], 8);
    a0[k] += __shfl_xor(a0[k], 16);
    a0[k] += __shfl_xor(a0[k], 32);
  }
  if (sub == 0) {
    float* ap = agg + ((size_t)node << 6) + pass * 32 + fo;
    *(float4*)(ap)     = make_float4(a0[0], a0[1], a0[2], a0[3]);
    *(float4*)(ap + 4) = make_float4(a0[4], a0[5], a0[6], a0[7]);
  }
}

// ===========================================================================
// Dense: out = [relu](agg @ W_rel + b + h @ W_root). Weights in registers,
// readlane broadcast, zero LDS. agg fp32 [n][64]; h/out split half-tables.
// ===========================================================================
__global__ __launch_bounds__(64) void dense_kernel(
    const float* __restrict__ agg,
    const u16* __restrict__ hLo, const u16* __restrict__ hHi,
    const float* __restrict__ Wrel, const float* __restrict__ brel,
    const float* __restrict__ Wroot,
    u16* __restrict__ outLo, u16* __restrict__ outHi,
    int n_nodes, int do_relu) {
  int lane = threadIdx.x;
  float wrel[D], wroot[D];
#pragma unroll
  for (int k = 0; k < D; k++) {
    wrel[k] = Wrel[k * D + lane];
    wroot[k] = Wroot[k * D + lane];
  }
  float b = brel[lane];
  const u16* hsrc = (lane < 32) ? hLo : hHi;
  u16* odst = (lane < 32) ? outLo : outHi;
  int lf = lane & 31;

  for (int n = blockIdx.x; n < n_nodes; n += gridDim.x) {
    float va = agg[((size_t)n << 6) + lane];
    float vx = bf2f(hsrc[((size_t)n << 5) + lf]);
    float acc = b;
#pragma unroll
    for (int k = 0; k < D; k++) {
      float sa = __int_as_float(__builtin_amdgcn_readlane(__float_as_int(va), k));
      float sx = __int_as_float(__builtin_amdgcn_readlane(__float_as_int(vx), k));
      acc = fmaf(sa, wrel[k], acc);
      acc = fmaf(sx, wroot[k], acc);
    }
    if (do_relu) acc = fmaxf(acc, 0.0f);
    odst[((size_t)n << 5) + lf] = f2bf(acc);
  }
}

// ===========================================================================
// Pool + final fused: one block per graph; batch sorted -> binary-search the
// segment, mean into LDS, threads 0..15 apply the 64x16 linear.
// ===========================================================================
__global__ __launch_bounds__(256) void pool_final_kernel(
    const u16* __restrict__ hLo, const u16* __restrict__ hHi,
    const int* __restrict__ batch,
    const float* __restrict__ Wlin, const float* __restrict__ blin,
    float* __restrict__ out, int n_nodes) {
  __shared__ int seg[2];
  __shared__ float red[256];
  __shared__ float pm[D];
  int g = blockIdx.x;
  if (threadIdx.x < 2) {
    int target = g + (int)threadIdx.x;
    int lo = 0, hi = n_nodes;
    while (lo < hi) {
      int mid = (lo + hi) >> 1;
      if (batch[mid] < target) lo = mid + 1; else hi = mid;
    }
    seg[threadIdx.x] = lo;
  }
  __syncthreads();
  int start = seg[0], end = seg[1];
  int f = threadIdx.x & 63, sub = threadIdx.x >> 6;
  const u16* hs = (f < 32) ? hLo : hHi;
  int lf = f & 31;
  float acc = 0.0f;
  for (int n = start + sub; n < end; n += 4) acc += bf2f(hs[((size_t)n << 5) + lf]);
  red[threadIdx.x] = acc;
  __syncthreads();
  if (sub == 0) {
    float v = red[f] + red[64 + f] + red[128 + f] + red[192 + f];
    float cnt = (float)(end - start);
    pm[f] = v / fmaxf(cnt, 1.0f);
  }
  __syncthreads();
  if (threadIdx.x < D_OUT) {
    int o = threadIdx.x;
    float a = blin[o];
#pragma unroll
    for (int k = 0; k < D; k++) a = fmaf(pm[k], Wlin[k * D_OUT + o], a);
    out[g * D_OUT + o] = a;
  }
}

extern "C" void kernel_launch(void* const* d_in, const int* in_sizes, int n_in,
                              void* d_out, int out_size, void* d_ws, size_t ws_size,
                              hipStream_t stream) {
  const float* x     = (const float*)d_in[0];
  const int*   ei    = (const int*)d_in[1];
  const int*   batch = (const int*)d_in[3];
  const float* Wrel1 = (const float*)d_in[4];
  const float* brel1 = (const float*)d_in[5];
  const float* Wroot1= (const float*)d_in[6];
  const float* Wrel2 = (const float*)d_in[7];
  const float* brel2 = (const float*)d_in[8];
  const float* Wroot2= (const float*)d_in[9];
  const float* Wrel3 = (const float*)d_in[10];
  const float* brel3 = (const float*)d_in[11];
  const float* Wroot3= (const float*)d_in[12];
  const float* Wlin  = (const float*)d_in[13];
  const float* blin  = (const float*)d_in[14];
  float* out = (float*)d_out;

  const int n_edges = in_sizes[1] / 2;
  const int n_nodes = in_sizes[0] / D;
  const int* src = ei;
  const int* dst = ei + n_edges;
  const int nbuck = (n_nodes + 255) >> 8;  // 196

  // ---- workspace carve-up (binned aliases agg: binned dead after csr) ----
  char* p = (char*)d_ws;
  size_t binned_bytes = (size_t)nbuck * BCAP * sizeof(u32);
  size_t agg_bytes = (size_t)n_nodes * D * sizeof(float);
  u32* binned  = (u32*)p;
  float* agg   = (float*)p;
  p += (binned_bytes > agg_bytes ? binned_bytes : agg_bytes);
  int* cursors  = (int*)p;   p += 256 * sizeof(int);
  int* offsets  = (int*)p;   p += (size_t)(n_nodes + 4) * sizeof(int);
  size_t half = (size_t)n_nodes * 32 * sizeof(u16);  // 3.2MB per half-table
  u16* hXLo = (u16*)p; p += half;
  u16* hXHi = (u16*)p; p += half;
  u16* h1Lo = (u16*)p; p += half;
  u16* h1Hi = (u16*)p; p += half;
  u16* h2Lo = (u16*)p; p += half;
  u16* h2Hi = (u16*)p; p += half;
  u16* h3Lo = (u16*)p; p += half;
  u16* h3Hi = (u16*)p; p += half;
  u16* csr_src  = (u16*)p;   p += (size_t)n_edges * sizeof(u16);

  const int bin_blocks = (n_edges + TILE - 1) / TILE;
  const int nb = (n_nodes + 3) / 4;        // gather blocks per pass
  const int dense_blocks = 3072;
  const int cvt_n4 = n_nodes * D / 4;

  // ---- CSR build (LDS counting sort) + x->bf16 split halves ----
  cvt_bf16_kernel<<<(cvt_n4 + 255) / 256, 256, 0, stream>>>(x, hXLo, hXHi, cvt_n4, cursors, nbuck);
  bin_kernel<<<bin_blocks, 256, 0, stream>>>(src, dst, cursors, binned, n_edges, nbuck);
  csr_kernel<<<nbuck, 256, 0, stream>>>(binned, cursors, csr_src, offsets, n_nodes, nbuck);

  // ---- layer 1 ----
  gather_kernel<<<2 * nb, 256, 0, stream>>>(hXLo, hXHi, offsets, csr_src, agg, n_nodes, nb);
  dense_kernel<<<dense_blocks, 64, 0, stream>>>(agg, hXLo, hXHi, Wrel1, brel1, Wroot1, h1Lo, h1Hi, n_nodes, 1);

  // ---- layer 2 ----
  gather_kernel<<<2 * nb, 256, 0, stream>>>(h1Lo, h1Hi, offsets, csr_src, agg, n_nodes, nb);
  dense_kernel<<<dense_blocks, 64, 0, stream>>>(agg, h1Lo, h1Hi, Wrel2, brel2, Wroot2, h2Lo, h2Hi, n_nodes, 1);

  // ---- layer 3 (no relu) ----
  gather_kernel<<<2 * nb, 256, 0, stream>>>(h2Lo, h2Hi, offsets, csr_src, agg, n_nodes, nb);
  dense_kernel<<<dense_blocks, 64, 0, stream>>>(agg, h2Lo, h2Hi, Wrel3, brel3, Wroot3, h3Lo, h3Hi, n_nodes, 0);

  // ---- pool + final linear (fused) ----
  pool_final_kernel<<<N_GRAPHS, 256, 0, stream>>>(h3Lo, h3Hi, batch, Wlin, blin, out, n_nodes);
}